// Round 1
// baseline (1627.021 us; speedup 1.0000x reference)
//
#include <hip/hip_runtime.h>
#include <stdint.h>

typedef _Float16 f16;
typedef _Float16 f16x8 __attribute__((ext_vector_type(8)));
typedef float f32x4 __attribute__((ext_vector_type(4)));

#define B_ROWS 32768
#define DIM 512
#define NP 8
#define NK 10

typedef __attribute__((address_space(3))) unsigned int lds_u32;
typedef __attribute__((address_space(1))) const unsigned int gbl_u32;

__device__ __forceinline__ void gload_lds16(const void* g, void* l) {
  __builtin_amdgcn_global_load_lds((gbl_u32*)(uintptr_t)g, (lds_u32*)(uintptr_t)l, 16, 0, 0);
}

// ---------------- prep kernels ----------------

__global__ void split_kernel(const float* __restrict__ src, f16* __restrict__ hi,
                             f16* __restrict__ lo, int n) {
  int i = blockIdx.x * 256 + threadIdx.x;
  int stride = gridDim.x * 256;
  for (; i < n; i += stride) {
    float v = src[i];
    f16 h = (f16)v;
    hi[i] = h;
    lo[i] = (f16)(v - (float)h);
  }
}

__global__ void emean_kernel(const float* __restrict__ E, float* __restrict__ Emean) {
  int i = blockIdx.x * 256 + threadIdx.x;
  if (i < NK * DIM) {
    float s = 0.f;
#pragma unroll
    for (int p = 0; p < NP; ++p) s += E[p * NK * DIM + i];
    Emean[i] = s * 0.125f;
  }
}

__global__ void enorm_kernel(const float* __restrict__ E, const float* __restrict__ Emean,
                             float* __restrict__ E2, float* __restrict__ E2m) {
  int bid = blockIdx.x;  // 0..79 -> E2[p*10+k]; 80..89 -> E2m[k]
  const float* src = (bid < 80) ? (E + (size_t)bid * DIM) : (Emean + (size_t)(bid - 80) * DIM);
  int lane = threadIdx.x;  // block = 64
  float s = 0.f;
  for (int i = lane; i < DIM; i += 64) {
    float v = src[i];
    s = fmaf(v, v, s);
  }
#pragma unroll
  for (int m = 1; m < 64; m <<= 1) s += __shfl_xor(s, m, 64);
  if (lane == 0) {
    if (bid < 80) E2[bid] = s;
    else E2m[bid - 80] = s;
  }
}

// ---------------- split-fp16 GEMM-BT: C[m][n] = sum_k A[m][k]*B[n][k] ----------------
// A = Ah + Al, B = Bh + Bl; products (Ah,Bh),(Al,Bh),(Ah,Bl) -> ~fp32 accuracy.
// EPI 0: relu(acc+bias) split to Oh/Ol fp16.  EPI 1: acc+bias -> Of fp32.

template <int EPI>
__global__ __launch_bounds__(256) void gemm_split(
    const f16* __restrict__ Ah, const f16* __restrict__ Al,
    const f16* __restrict__ Bh, const f16* __restrict__ Bl,
    const float* __restrict__ bias,
    f16* __restrict__ Oh, f16* __restrict__ Ol, float* __restrict__ Of) {
  __shared__ f16 smem[32768];  // 64 KB: [buf][A 8192 f16 | B 8192 f16]
  const int tid = threadIdx.x;
  const int lane = tid & 63;
  const int wave = tid >> 6;
  const int wr = wave >> 1, wc = wave & 1;
  const int mb = blockIdx.x >> 2, nb = blockIdx.x & 3;
  const int m0 = mb * 128, n0 = nb * 128;

  const f16* APl[3] = {Ah, Al, Ah};
  const f16* BPl[3] = {Bh, Bh, Bl};

  f32x4 acc[4][4] = {};

  auto stage = [&](int buf, const f16* gA, const f16* gB, int k0) {
    f16* sA = smem + buf * 16384;
    f16* sB = sA + 8192;
#pragma unroll
    for (int j = 0; j < 4; ++j) {
      int r = j * 32 + (tid >> 3);
      int c = ((tid & 7) ^ (r & 7)) * 8;  // pre-swizzled source col (fp16 elems)
      gload_lds16(gA + (size_t)(m0 + r) * DIM + k0 + c, sA + j * 2048 + tid * 8);
      gload_lds16(gB + (size_t)(n0 + r) * DIM + k0 + c, sB + j * 2048 + tid * 8);
    }
  };

  stage(0, APl[0], BPl[0], 0);
  __syncthreads();

  const int g = lane >> 4, rl = lane & 15;

  for (int s = 0; s < 24; ++s) {
    int nx = s + 1;
    if (nx < 24) stage(nx & 1, APl[nx >> 3], BPl[nx >> 3], (nx & 7) * 64);
    const char* sA = (const char*)(smem + (s & 1) * 16384);
    const char* sB = sA + 16384;  // bytes
    f16x8 af[4][2], bf[4][2];
#pragma unroll
    for (int i = 0; i < 4; ++i) {
      int ra = wr * 64 + i * 16 + rl;
      int rb = wc * 64 + i * 16 + rl;
#pragma unroll
      for (int kk = 0; kk < 2; ++kk) {
        int cb = kk * 64 + g * 16;
        af[i][kk] = *(const f16x8*)(sA + ra * 128 + (cb ^ ((ra & 7) << 4)));
        bf[i][kk] = *(const f16x8*)(sB + rb * 128 + (cb ^ ((rb & 7) << 4)));
      }
    }
#pragma unroll
    for (int i = 0; i < 4; ++i)
#pragma unroll
      for (int jn = 0; jn < 4; ++jn)
#pragma unroll
        for (int kk = 0; kk < 2; ++kk)
          acc[i][jn] = __builtin_amdgcn_mfma_f32_16x16x32_f16(af[i][kk], bf[jn][kk], acc[i][jn], 0, 0, 0);
    __syncthreads();
  }

#pragma unroll
  for (int jn = 0; jn < 4; ++jn) {
    int c = n0 + wc * 64 + jn * 16 + rl;
    float bv = bias[c];
#pragma unroll
    for (int i = 0; i < 4; ++i) {
      int r0 = m0 + wr * 64 + i * 16 + g * 4;
#pragma unroll
      for (int r = 0; r < 4; ++r) {
        float z = acc[i][jn][r] + bv;
        size_t off = (size_t)(r0 + r) * DIM + c;
        if (EPI == 0) {
          z = fmaxf(z, 0.f);
          f16 h = (f16)z;
          Oh[off] = h;
          Ol[off] = (f16)(z - (float)h);
        } else {
          Of[off] = z;
        }
      }
    }
  }
}

// ---------------- distances: one wave per (p,b) row ----------------

__global__ __launch_bounds__(256) void dist_kernel(const float* __restrict__ Z,
                                                   const float* __restrict__ E,
                                                   const float* __restrict__ E2,
                                                   float* __restrict__ distOut) {
  const int p = blockIdx.y;
  __shared__ float Es[NK * DIM];
  for (int i = threadIdx.x; i < NK * DIM; i += 256) Es[i] = E[(size_t)p * NK * DIM + i];
  __syncthreads();
  const int lane = threadIdx.x & 63, wave = threadIdx.x >> 6;
  for (int rr = 0; rr < 16; ++rr) {
    int b = blockIdx.x * 64 + wave * 16 + rr;
    const float* zr = Z + ((size_t)p * B_ROWS + b) * DIM;
    float s2 = 0.f;
    float d[NK] = {};
#pragma unroll
    for (int j = 0; j < 8; ++j) {
      float z = zr[j * 64 + lane];
      s2 = fmaf(z, z, s2);
#pragma unroll
      for (int k = 0; k < NK; ++k) d[k] = fmaf(z, Es[k * DIM + j * 64 + lane], d[k]);
    }
#pragma unroll
    for (int m = 1; m < 64; m <<= 1) {
      s2 += __shfl_xor(s2, m, 64);
#pragma unroll
      for (int k = 0; k < NK; ++k) d[k] += __shfl_xor(d[k], m, 64);
    }
    if (lane == 0) {
      float* o = distOut + ((size_t)p * B_ROWS + b) * NK;
#pragma unroll
      for (int k = 0; k < NK; ++k) o[k] = s2 + E2[p * NK + k] - 2.f * d[k];
    }
  }
}

// ---------------- argmin + vq_z + all_vq_loss + changed_vq_z ----------------

__global__ __launch_bounds__(256) void final_kernel(
    const float* __restrict__ X, const float* __restrict__ distOut,
    const float* __restrict__ Emean, const float* __restrict__ E2m,
    const int* __restrict__ label, float* __restrict__ vq_z,
    float* __restrict__ loss, float* __restrict__ changed) {
  __shared__ float Em[NK * DIM];
  __shared__ float e2s[NK];
  for (int i = threadIdx.x; i < NK * DIM; i += 256) Em[i] = Emean[i];
  if (threadIdx.x < NK) e2s[threadIdx.x] = E2m[threadIdx.x];
  __syncthreads();
  const int lane = threadIdx.x & 63, wave = threadIdx.x >> 6;
  const int pl = lane & 7, kh = lane >> 3;
  for (int rr = 0; rr < 4; ++rr) {
    int b = blockIdx.x * 16 + wave * 4 + rr;
    // sum over p of distances; lanes: p = lane&7, k = lane>>3 (k=0..7), second fetch covers k=8,9
    size_t dbase = ((size_t)pl * B_ROWS + b) * NK;
    float v0 = distOut[dbase + kh];
    float v1 = (lane < 16) ? distOut[dbase + 8 + kh] : 0.f;
#pragma unroll
    for (int m = 1; m < 8; m <<= 1) {
      v0 += __shfl_xor(v0, m, 64);
      v1 += __shfl_xor(v1, m, 64);
    }
    float a[NK];
#pragma unroll
    for (int k = 0; k < 8; ++k) a[k] = __shfl(v0, k * 8, 64);
    a[8] = __shfl(v1, 0, 64);
    a[9] = __shfl(v1, 8, 64);
    int idx = 0;
    float mn = a[0];
#pragma unroll
    for (int k = 1; k < NK; ++k) {
      if (a[k] < mn) { mn = a[k]; idx = k; }
    }
    // x-dependent terms
    const float* xr = X + (size_t)b * DIM;
    float sx = 0.f, dx[NK] = {};
#pragma unroll
    for (int j = 0; j < 8; ++j) {
      float x = xr[j * 64 + lane];
      sx = fmaf(x, x, sx);
#pragma unroll
      for (int k = 0; k < NK; ++k) dx[k] = fmaf(x, Em[k * DIM + j * 64 + lane], dx[k]);
    }
#pragma unroll
    for (int m = 1; m < 64; m <<= 1) {
      sx += __shfl_xor(sx, m, 64);
#pragma unroll
      for (int k = 0; k < NK; ++k) dx[k] += __shfl_xor(dx[k], m, 64);
    }
    if (lane == 0) {
#pragma unroll
      for (int k = 0; k < NK; ++k)
        loss[(size_t)k * B_ROWS + b] = 1.25f * (sx - 2.f * dx[k] + e2s[k]);
    }
    int lab = label[b];
#pragma unroll
    for (int j = 0; j < 8; ++j) {
      int c = j * 64 + lane;
      vq_z[(size_t)b * DIM + c] = Em[idx * DIM + c];
      changed[(size_t)b * DIM + c] = Em[lab * DIM + c];
    }
  }
}

// ---------------- all_vq_z broadcast ----------------

__global__ void bcast_kernel(const float* __restrict__ Emean, float4* __restrict__ out) {
  const float4* Em4 = (const float4*)Emean;
  size_t n = (size_t)NK * B_ROWS * (DIM / 4);
  for (size_t i = (size_t)blockIdx.x * blockDim.x + threadIdx.x; i < n;
       i += (size_t)gridDim.x * blockDim.x) {
    size_t kb = i >> 7;          // / (DIM/4)
    int d4 = (int)(i & 127);
    int k = (int)(kb >> 15);     // / B_ROWS
    out[i] = Em4[k * 128 + d4];
  }
}

// ---------------- launch ----------------

extern "C" void kernel_launch(void* const* d_in, const int* in_sizes, int n_in,
                              void* d_out, int out_size, void* d_ws, size_t ws_size,
                              hipStream_t stream) {
  const float* X = (const float*)d_in[0];
  const float* W1 = (const float*)d_in[1];
  const float* b1 = (const float*)d_in[2];
  const float* W2 = (const float*)d_in[3];
  const float* b2 = (const float*)d_in[4];
  const float* E = (const float*)d_in[5];
  const int* lab = (const int*)d_in[6];
  float* out = (float*)d_out;

  // output layout (flat f32, return order)
  float* vq_z = out;                               // 16,777,216
  float* dist = out + 16777216;                    // 2,621,440
  float* avz = out + 16777216 + 2621440;           // 167,772,160
  float* loss = avz + 167772160;                   // 327,680
  float* chg = loss + 327680;                      // 16,777,216

  // scratch carved from output regions (overwritten by final/bcast kernels at the end):
  f16* Xh = (f16*)vq_z;                      // 16.7M f16 = 33.5 MB
  f16* Xl = Xh + 16777216;                   // fills the 67 MB vq_z region exactly
  float* Z = avz;                            // [8][32768][512] f32 = 537 MB (avz region is 671 MB)
  f16* Hh = (f16*)(avz + 134217728);         // per-p H planes in avz tail
  f16* Hl = Hh + 16777216;

  // small ws allocations (W splits + E stats) ~17 MB
  char* w = (char*)d_ws;
  f16* W1h = (f16*)w; w += 4194304;
  f16* W1l = (f16*)w; w += 4194304;
  f16* W2h = (f16*)w; w += 4194304;
  f16* W2l = (f16*)w; w += 4194304;
  float* Emean = (float*)w; w += NK * DIM * 4;
  float* E2 = (float*)w; w += 512;
  float* E2m = (float*)w; w += 256;

  split_kernel<<<2048, 256, 0, stream>>>(X, Xh, Xl, 16777216);
  split_kernel<<<512, 256, 0, stream>>>(W1, W1h, W1l, 2097152);
  split_kernel<<<512, 256, 0, stream>>>(W2, W2h, W2l, 2097152);
  emean_kernel<<<20, 256, 0, stream>>>(E, Emean);
  enorm_kernel<<<90, 64, 0, stream>>>(E, Emean, E2, E2m);

  for (int p = 0; p < NP; ++p) {
    gemm_split<0><<<1024, 256, 0, stream>>>(Xh, Xl, W1h + (size_t)p * 262144,
                                            W1l + (size_t)p * 262144, b1 + p * 512, Hh, Hl,
                                            nullptr);
    gemm_split<1><<<1024, 256, 0, stream>>>(Hh, Hl, W2h + (size_t)p * 262144,
                                            W2l + (size_t)p * 262144, b2 + p * 512, nullptr,
                                            nullptr, Z + (size_t)p * 16777216);
  }

  dist_kernel<<<dim3(512, 8), 256, 0, stream>>>(Z, E, E2, dist);
  final_kernel<<<2048, 256, 0, stream>>>(X, dist, Emean, E2m, lab, vq_z, loss, chg);
  bcast_kernel<<<4096, 256, 0, stream>>>(Emean, (float4*)avz);
}

// Round 2
// 1405.862 us; speedup vs baseline: 1.1573x; 1.1573x over previous
//
#include <hip/hip_runtime.h>
#include <stdint.h>

typedef _Float16 f16;
typedef _Float16 f16x8 __attribute__((ext_vector_type(8)));
typedef float f32x4 __attribute__((ext_vector_type(4)));

#define B_ROWS 32768
#define DIM 512
#define NP 8
#define NK 10

typedef __attribute__((address_space(3))) unsigned int lds_u32;
typedef __attribute__((address_space(1))) const unsigned int gbl_u32;

__device__ __forceinline__ void gload_lds16(const void* g, void* l) {
  __builtin_amdgcn_global_load_lds((gbl_u32*)(uintptr_t)g, (lds_u32*)(uintptr_t)l, 16, 0, 0);
}

// ---------------- prep kernels ----------------

__global__ void split_kernel(const float* __restrict__ src, f16* __restrict__ hi,
                             f16* __restrict__ lo, int n) {
  int i = blockIdx.x * 256 + threadIdx.x;
  int stride = gridDim.x * 256;
  for (; i < n; i += stride) {
    float v = src[i];
    f16 h = (f16)v;
    hi[i] = h;
    lo[i] = (f16)(v - (float)h);
  }
}

__global__ void emean_kernel(const float* __restrict__ E, float* __restrict__ Emean) {
  int i = blockIdx.x * 256 + threadIdx.x;
  if (i < NK * DIM) {
    float s = 0.f;
#pragma unroll
    for (int p = 0; p < NP; ++p) s += E[p * NK * DIM + i];
    Emean[i] = s * 0.125f;
  }
}

__global__ void enorm_kernel(const float* __restrict__ E, const float* __restrict__ Emean,
                             float* __restrict__ E2, float* __restrict__ E2m) {
  int bid = blockIdx.x;  // 0..79 -> E2[p*10+k]; 80..89 -> E2m[k]
  const float* src = (bid < 80) ? (E + (size_t)bid * DIM) : (Emean + (size_t)(bid - 80) * DIM);
  int lane = threadIdx.x;  // block = 64
  float s = 0.f;
  for (int i = lane; i < DIM; i += 64) {
    float v = src[i];
    s = fmaf(v, v, s);
  }
#pragma unroll
  for (int m = 1; m < 64; m <<= 1) s += __shfl_xor(s, m, 64);
  if (lane == 0) {
    if (bid < 80) E2[bid] = s;
    else E2m[bid - 80] = s;
  }
}

// ---------------- 8-phase 256x256 split-fp16 GEMM-BT ----------------
// C[m][n] = sum_k A[m][k]*B[n][k]; A=Ah+Al, B=Bh+Bl; products (Ah,Bh),(Ah,Bl),(Al,Bh)
// serialized over 24 K-tiles of 64 (k-major product order for L2 reuse).
// EPI 0: relu(acc+bias) split -> Oh/Ol fp16 planes (ldo).
// EPI 1: z=acc+bias; per-wave 64-col distance partials -> part[p][ch][row][12].

template <int EPI, int NBN>
__global__ __launch_bounds__(512, 2) void gemm8(
    const f16* __restrict__ Ah_, const f16* __restrict__ Al_, int lda, int apitch,
    const f16* __restrict__ Bh_, const f16* __restrict__ Bl_, int bstride,
    const float* __restrict__ bias_, int bias_ps,
    f16* __restrict__ Oh, f16* __restrict__ Ol, int ldo,
    float* __restrict__ part, const float* __restrict__ Efull) {
  __shared__ f16 smem[65536];  // 128 KB: 2 buffers x [A0 A1 B0 B1] (16KB halves)
  const int tid = threadIdx.x;
  const int lane = tid & 63;
  const int wave = tid >> 6;      // 0..7
  const int wr = wave >> 2;       // 0..1
  const int wc = wave & 3;        // 0..3
  const int g = lane >> 4, rl = lane & 15;
  const int p = blockIdx.z;

  // bijective XCD swizzle (gridDim.x divisible by 8)
  const int q8 = gridDim.x >> 3;
  const int bid = blockIdx.x;
  const int swz = (bid & 7) * q8 + (bid >> 3);
  const int bm = swz / NBN, bn = swz % NBN;
  const int m0 = bm * 256, n0 = bn * 256;

  const f16* Ahp = Ah_ + (size_t)p * apitch;
  const f16* Alp = Al_ + (size_t)p * apitch;
  const f16* Bhp = Bh_ + (size_t)p * bstride;
  const f16* Blp = Bl_ + (size_t)p * bstride;

  f32x4 acc[8][4] = {};

  auto stage_half = [&](int t, int ht) {
    if (t >= 24) return;
    int pr = t % 3;  // 0:(Ah,Bh) 1:(Ah,Bl) 2:(Al,Bh)
    const f16* As = (pr == 2) ? Alp : Ahp;
    const f16* Bs = (pr == 1) ? Blp : Bhp;
    int k0 = (t / 3) * 64;
    f16* dst = smem + (t & 1) * 32768 + ht * 8192;
#pragma unroll
    for (int rnd = 0; rnd < 2; ++rnd) {
      int w = rnd * 512 + tid;
      int row = w >> 3;
      int col = ((w & 7) ^ (row & 7)) * 8;  // pre-swizzled source col
      const f16* src = (ht < 2)
          ? As + (size_t)(m0 + ht * 128 + row) * lda + k0 + col
          : Bs + (size_t)(n0 + (ht - 2) * 128 + row) * 512 + k0 + col;
      gload_lds16(src, dst + (size_t)w * 8);
    }
  };

  // per-thread constant offsets for swizzled frag reads
  const int ck0 = ((0 * 4 + g) ^ (rl & 7)) << 4;  // kk=0
  const int ck1 = ((1 * 4 + g) ^ (rl & 7)) << 4;  // kk=1
  const int abase = wr * 16384 + rl * 128;
  const int bbase = 32768 + (wc >> 1) * 16384 + (wc & 1) * 8192 + rl * 128;

  // ---- prologue: tile0 full + tile1 A-halves; vmcnt(4) -> tile0 resident
  stage_half(0, 0); stage_half(0, 1); stage_half(0, 2); stage_half(0, 3);
  stage_half(1, 0); stage_half(1, 1);
  asm volatile("s_waitcnt vmcnt(4)" ::: "memory");
  __builtin_amdgcn_s_barrier();

  for (int t = 0; t < 24; ++t) {
    const char* sb = (const char*)(smem + (t & 1) * 32768);
    f16x8 afA[4][2], afB[4][2], bfA[2][2], bfB[2][2];

    // ===== phase 1: read A0-3 + B0-1; stage B halves of t+1 (other buffer)
#pragma unroll
    for (int i = 0; i < 4; ++i) {
      afA[i][0] = *(const f16x8*)(sb + abase + i * 2048 + ck0);
      afA[i][1] = *(const f16x8*)(sb + abase + i * 2048 + ck1);
    }
#pragma unroll
    for (int j = 0; j < 2; ++j) {
      bfA[j][0] = *(const f16x8*)(sb + bbase + j * 2048 + ck0);
      bfA[j][1] = *(const f16x8*)(sb + bbase + j * 2048 + ck1);
    }
    stage_half(t + 1, 2); stage_half(t + 1, 3);
    asm volatile("" ::: "memory");
    __builtin_amdgcn_s_barrier();
    __builtin_amdgcn_s_setprio(1);
#pragma unroll
    for (int i = 0; i < 4; ++i)
#pragma unroll
      for (int j = 0; j < 2; ++j)
#pragma unroll
        for (int kk = 0; kk < 2; ++kk)
          acc[i][j] = __builtin_amdgcn_mfma_f32_16x16x32_f16(afA[i][kk], bfA[j][kk], acc[i][j], 0, 0, 0);
    __builtin_amdgcn_s_setprio(0);
    asm volatile("" ::: "memory");
    __builtin_amdgcn_s_barrier();

    // ===== phase 2: read B2-3; MFMA quadrant (i0-3 x jn2-3)
#pragma unroll
    for (int j = 0; j < 2; ++j) {
      bfB[j][0] = *(const f16x8*)(sb + bbase + (j + 2) * 2048 + ck0);
      bfB[j][1] = *(const f16x8*)(sb + bbase + (j + 2) * 2048 + ck1);
    }
    asm volatile("" ::: "memory");
    __builtin_amdgcn_s_barrier();
    __builtin_amdgcn_s_setprio(1);
#pragma unroll
    for (int i = 0; i < 4; ++i)
#pragma unroll
      for (int j = 0; j < 2; ++j)
#pragma unroll
        for (int kk = 0; kk < 2; ++kk)
          acc[i][j + 2] = __builtin_amdgcn_mfma_f32_16x16x32_f16(afA[i][kk], bfB[j][kk], acc[i][j + 2], 0, 0, 0);
    __builtin_amdgcn_s_setprio(0);
    asm volatile("" ::: "memory");
    __builtin_amdgcn_s_barrier();

    // ===== phase 3: read A4-7; MFMA quadrant (i4-7 x jn0-1)
#pragma unroll
    for (int i = 0; i < 4; ++i) {
      afB[i][0] = *(const f16x8*)(sb + abase + (i + 4) * 2048 + ck0);
      afB[i][1] = *(const f16x8*)(sb + abase + (i + 4) * 2048 + ck1);
    }
    asm volatile("" ::: "memory");
    __builtin_amdgcn_s_barrier();
    __builtin_amdgcn_s_setprio(1);
#pragma unroll
    for (int i = 0; i < 4; ++i)
#pragma unroll
      for (int j = 0; j < 2; ++j)
#pragma unroll
        for (int kk = 0; kk < 2; ++kk)
          acc[i + 4][j] = __builtin_amdgcn_mfma_f32_16x16x32_f16(afB[i][kk], bfA[j][kk], acc[i + 4][j], 0, 0, 0);
    __builtin_amdgcn_s_setprio(0);
    asm volatile("" ::: "memory");
    __builtin_amdgcn_s_barrier();

    // ===== phase 4: stage A halves of t+2 (this buffer; all its A reads done);
    //               counted vmcnt -> tile t+1 resident; MFMA quadrant (i4-7 x jn2-3)
    stage_half(t + 2, 0); stage_half(t + 2, 1);
    if (t < 22) asm volatile("s_waitcnt vmcnt(4)" ::: "memory");
    else        asm volatile("s_waitcnt vmcnt(0)" ::: "memory");
    __builtin_amdgcn_s_barrier();
    __builtin_amdgcn_s_setprio(1);
#pragma unroll
    for (int i = 0; i < 4; ++i)
#pragma unroll
      for (int j = 0; j < 2; ++j)
#pragma unroll
        for (int kk = 0; kk < 2; ++kk)
          acc[i + 4][j + 2] = __builtin_amdgcn_mfma_f32_16x16x32_f16(afB[i][kk], bfB[j][kk], acc[i + 4][j + 2], 0, 0, 0);
    __builtin_amdgcn_s_setprio(0);
    asm volatile("" ::: "memory");
    __builtin_amdgcn_s_barrier();
  }

  // ---------------- epilogues ----------------
  if (EPI == 0) {
#pragma unroll
    for (int jn = 0; jn < 4; ++jn) {
      int cg = n0 + wc * 64 + jn * 16 + rl;
      float bv = bias_[cg];
#pragma unroll
      for (int i = 0; i < 8; ++i) {
#pragma unroll
        for (int r = 0; r < 4; ++r) {
          int row = m0 + wr * 128 + i * 16 + g * 4 + r;
          float z = acc[i][jn][r] + bv;
          z = fmaxf(z, 0.f);
          f16 h = (f16)z;
          size_t off = (size_t)row * ldo + cg;
          Oh[off] = h;
          Ol[off] = (f16)(z - (float)h);
        }
      }
    }
  } else {
    const float* Ep = Efull + (size_t)p * (NK * DIM);
    const float* bp = bias_ + (size_t)p * bias_ps;
    float ev[NK][4], bvals[4];
#pragma unroll
    for (int jn = 0; jn < 4; ++jn) {
      int c = n0 + wc * 64 + jn * 16 + rl;
      bvals[jn] = bp[c];
#pragma unroll
      for (int k = 0; k < NK; ++k) ev[k][jn] = Ep[k * DIM + c];
    }
    const int ch = bn * 4 + wc;
    float* pb = part + (size_t)(p * 8 + ch) * B_ROWS * 12;
#pragma unroll
    for (int i = 0; i < 8; ++i) {
#pragma unroll
      for (int r = 0; r < 4; ++r) {
        float qv[11];
        qv[0] = 0.f;
#pragma unroll
        for (int k = 0; k < NK; ++k) qv[1 + k] = 0.f;
#pragma unroll
        for (int jn = 0; jn < 4; ++jn) {
          float z = acc[i][jn][r] + bvals[jn];
          qv[0] = fmaf(z, z, qv[0]);
#pragma unroll
          for (int k = 0; k < NK; ++k) qv[1 + k] = fmaf(z, ev[k][jn], qv[1 + k]);
        }
#pragma unroll
        for (int m = 1; m < 16; m <<= 1)
#pragma unroll
          for (int u = 0; u < 11; ++u) qv[u] += __shfl_xor(qv[u], m, 64);
        if (rl == 0) {
          int row = m0 + wr * 128 + i * 16 + g * 4 + r;
          float* o = pb + (size_t)row * 12;
#pragma unroll
          for (int u = 0; u < 11; ++u) o[u] = qv[u];
        }
      }
    }
  }
}

// ---------------- distance partial reduce ----------------

__global__ __launch_bounds__(256) void reduce_dist(const float* __restrict__ part,
                                                   const float* __restrict__ E2,
                                                   float* __restrict__ dist) {
  int idx = blockIdx.x * 256 + threadIdx.x;  // p*32768 + b
  int pp = idx >> 15, b = idx & 32767;
  float s2 = 0.f, d[NK];
#pragma unroll
  for (int k = 0; k < NK; ++k) d[k] = 0.f;
  const float* q = part + ((size_t)(pp * 8) * B_ROWS + b) * 12;
#pragma unroll
  for (int ch = 0; ch < 8; ++ch) {
    const float* qc = q + (size_t)ch * B_ROWS * 12;
    s2 += qc[0];
#pragma unroll
    for (int k = 0; k < NK; ++k) d[k] += qc[1 + k];
  }
  float* o = dist + (size_t)idx * NK;
#pragma unroll
  for (int k = 0; k < NK; ++k) o[k] = s2 + E2[pp * NK + k] - 2.f * d[k];
}

// ---------------- argmin + vq_z + all_vq_loss + changed_vq_z ----------------

__global__ __launch_bounds__(256) void final_kernel(
    const float* __restrict__ X, const float* __restrict__ distOut,
    const float* __restrict__ Emean, const float* __restrict__ E2m,
    const int* __restrict__ label, float* __restrict__ vq_z,
    float* __restrict__ loss, float* __restrict__ changed) {
  __shared__ float Em[NK * DIM];
  __shared__ float e2s[NK];
  for (int i = threadIdx.x; i < NK * DIM; i += 256) Em[i] = Emean[i];
  if (threadIdx.x < NK) e2s[threadIdx.x] = E2m[threadIdx.x];
  __syncthreads();
  const int lane = threadIdx.x & 63, wave = threadIdx.x >> 6;
  const int pl = lane & 7, kh = lane >> 3;
  for (int rr = 0; rr < 4; ++rr) {
    int b = blockIdx.x * 16 + wave * 4 + rr;
    size_t dbase = ((size_t)pl * B_ROWS + b) * NK;
    float v0 = distOut[dbase + kh];
    float v1 = (lane < 16) ? distOut[dbase + 8 + kh] : 0.f;
#pragma unroll
    for (int m = 1; m < 8; m <<= 1) {
      v0 += __shfl_xor(v0, m, 64);
      v1 += __shfl_xor(v1, m, 64);
    }
    float a[NK];
#pragma unroll
    for (int k = 0; k < 8; ++k) a[k] = __shfl(v0, k * 8, 64);
    a[8] = __shfl(v1, 0, 64);
    a[9] = __shfl(v1, 8, 64);
    int idx = 0;
    float mn = a[0];
#pragma unroll
    for (int k = 1; k < NK; ++k) {
      if (a[k] < mn) { mn = a[k]; idx = k; }
    }
    const float* xr = X + (size_t)b * DIM;
    float sx = 0.f, dx[NK] = {};
#pragma unroll
    for (int j = 0; j < 8; ++j) {
      float x = xr[j * 64 + lane];
      sx = fmaf(x, x, sx);
#pragma unroll
      for (int k = 0; k < NK; ++k) dx[k] = fmaf(x, Em[k * DIM + j * 64 + lane], dx[k]);
    }
#pragma unroll
    for (int m = 1; m < 64; m <<= 1) {
      sx += __shfl_xor(sx, m, 64);
#pragma unroll
      for (int k = 0; k < NK; ++k) dx[k] += __shfl_xor(dx[k], m, 64);
    }
    if (lane == 0) {
#pragma unroll
      for (int k = 0; k < NK; ++k)
        loss[(size_t)k * B_ROWS + b] = 1.25f * (sx - 2.f * dx[k] + e2s[k]);
    }
    int lab = label[b];
#pragma unroll
    for (int j = 0; j < 8; ++j) {
      int c = j * 64 + lane;
      vq_z[(size_t)b * DIM + c] = Em[idx * DIM + c];
      changed[(size_t)b * DIM + c] = Em[lab * DIM + c];
    }
  }
}

// ---------------- all_vq_z broadcast ----------------

__global__ void bcast_kernel(const float* __restrict__ Emean, float4* __restrict__ out) {
  const float4* Em4 = (const float4*)Emean;
  size_t n = (size_t)NK * B_ROWS * (DIM / 4);
  for (size_t i = (size_t)blockIdx.x * blockDim.x + threadIdx.x; i < n;
       i += (size_t)gridDim.x * blockDim.x) {
    size_t kb = i >> 7;
    int d4 = (int)(i & 127);
    int k = (int)(kb >> 15);
    out[i] = Em4[k * 128 + d4];
  }
}

// ---------------- launch ----------------

extern "C" void kernel_launch(void* const* d_in, const int* in_sizes, int n_in,
                              void* d_out, int out_size, void* d_ws, size_t ws_size,
                              hipStream_t stream) {
  const float* X = (const float*)d_in[0];
  const float* W1 = (const float*)d_in[1];
  const float* b1 = (const float*)d_in[2];
  const float* W2 = (const float*)d_in[3];
  const float* b2 = (const float*)d_in[4];
  const float* E = (const float*)d_in[5];
  const int* lab = (const int*)d_in[6];
  float* out = (float*)d_out;

  // output layout (flat f32, return order)
  float* vq_z = out;                               // 16,777,216
  float* dist = out + 16777216;                    // 2,621,440
  float* avz = out + 16777216 + 2621440;           // 167,772,160
  float* loss = avz + 167772160;                   // 327,680
  float* chg = loss + 327680;                      // 16,777,216

  // scratch carved from output regions:
  f16* Xh = (f16*)vq_z;                       // 33.5 MB
  f16* Xl = Xh + 16777216;                    // fills vq_z region exactly
  f16* Hh = (f16*)avz;                        // stacked H [32768][4096] f16 = 268 MB
  f16* Hl = Hh + 134217728;                   // +268 MB (536 MB total in avz)
  float* part = avz + 134217728;              // byte off 536 MB; [8][8][32768][12] f32 = 100 MB

  // small ws allocations (~17 MB)
  char* w = (char*)d_ws;
  f16* W1h = (f16*)w; w += 4194304;
  f16* W1l = (f16*)w; w += 4194304;
  f16* W2h = (f16*)w; w += 4194304;
  f16* W2l = (f16*)w; w += 4194304;
  float* Emean = (float*)w; w += NK * DIM * 4;
  float* E2 = (float*)w; w += 512;
  float* E2m = (float*)w; w += 256;

  split_kernel<<<2048, 256, 0, stream>>>(X, Xh, Xl, 16777216);
  split_kernel<<<512, 256, 0, stream>>>(W1, W1h, W1l, 2097152);
  split_kernel<<<512, 256, 0, stream>>>(W2, W2h, W2l, 2097152);
  emean_kernel<<<20, 256, 0, stream>>>(E, Emean);
  enorm_kernel<<<90, 64, 0, stream>>>(E, Emean, E2, E2m);

  // GEMM1: [32768x512] x [4096x512]^T -> stacked H (relu+split)
  gemm8<0, 16><<<dim3(2048, 1, 1), 512, 0, stream>>>(
      Xh, Xl, 512, 0, W1h, W1l, 0, b1, 0, Hh, Hl, 4096, nullptr, nullptr);
  // GEMM2 (all p): [32768x512] x [512x512]^T -> fused distance partials
  gemm8<1, 2><<<dim3(256, 1, NP), 512, 0, stream>>>(
      Hh, Hl, 4096, 512, W2h, W2l, 262144, b2, 512, nullptr, nullptr, 0, part, E);

  reduce_dist<<<1024, 256, 0, stream>>>(part, E2, dist);
  final_kernel<<<2048, 256, 0, stream>>>(X, dist, Emean, E2m, lab, vq_z, loss, chg);
  bcast_kernel<<<4096, 256, 0, stream>>>(Emean, (float4*)avz);
}

// Round 3
// 1249.144 us; speedup vs baseline: 1.3025x; 1.1255x over previous
//
#include <hip/hip_runtime.h>
#include <stdint.h>

typedef _Float16 f16;
typedef _Float16 f16x8 __attribute__((ext_vector_type(8)));
typedef float f32x4 __attribute__((ext_vector_type(4)));

#define B_ROWS 32768
#define DIM 512
#define NP 8
#define NK 10

typedef __attribute__((address_space(3))) unsigned int lds_u32;
typedef __attribute__((address_space(1))) const unsigned int gbl_u32;

__device__ __forceinline__ void gload_lds16(const void* g, void* l) {
  __builtin_amdgcn_global_load_lds((gbl_u32*)(uintptr_t)g, (lds_u32*)(uintptr_t)l, 16, 0, 0);
}

// ---------------- prep kernels ----------------

__global__ void split_kernel(const float* __restrict__ src, f16* __restrict__ hi,
                             f16* __restrict__ lo, int n) {
  int i = blockIdx.x * 256 + threadIdx.x;
  int stride = gridDim.x * 256;
  for (; i < n; i += stride) {
    float v = src[i];
    f16 h = (f16)v;
    hi[i] = h;
    lo[i] = (f16)(v - (float)h);
  }
}

__global__ void emean_kernel(const float* __restrict__ E, float* __restrict__ Emean) {
  int i = blockIdx.x * 256 + threadIdx.x;
  if (i < NK * DIM) {
    float s = 0.f;
#pragma unroll
    for (int p = 0; p < NP; ++p) s += E[p * NK * DIM + i];
    Emean[i] = s * 0.125f;
  }
}

__global__ void enorm_kernel(const float* __restrict__ E, const float* __restrict__ Emean,
                             float* __restrict__ E2, float* __restrict__ E2m) {
  int bid = blockIdx.x;  // 0..79 -> E2[p*10+k]; 80..89 -> E2m[k]
  const float* src = (bid < 80) ? (E + (size_t)bid * DIM) : (Emean + (size_t)(bid - 80) * DIM);
  int lane = threadIdx.x;  // block = 64
  float s = 0.f;
  for (int i = lane; i < DIM; i += 64) {
    float v = src[i];
    s = fmaf(v, v, s);
  }
#pragma unroll
  for (int m = 1; m < 64; m <<= 1) s += __shfl_xor(s, m, 64);
  if (lane == 0) {
    if (bid < 80) E2[bid] = s;
    else E2m[bid - 80] = s;
  }
}

// Et[p][k][h] = sum_d W2[p][d][h]*E[p][k][d];  c[p][k] = b2[p]·E[p][k]
__global__ __launch_bounds__(512) void etilde_kernel(const float* __restrict__ W2,
                                                     const float* __restrict__ b2,
                                                     const float* __restrict__ E,
                                                     float* __restrict__ Et,
                                                     float* __restrict__ c_) {
  const int p = blockIdx.x / NK, k = blockIdx.x % NK;
  const int h = threadIdx.x;  // 512 threads
  __shared__ float Er[512];
  __shared__ float red[8];
  Er[h] = E[((size_t)p * NK + k) * DIM + h];
  __syncthreads();
  const float* Wp = W2 + (size_t)p * DIM * DIM;
  float s = 0.f;
#pragma unroll 8
  for (int d = 0; d < DIM; ++d) s = fmaf(Wp[(size_t)d * DIM + h], Er[d], s);
  Et[((size_t)p * NK + k) * DIM + h] = s;
  float t = b2[p * DIM + h] * Er[h];
#pragma unroll
  for (int m = 1; m < 64; m <<= 1) t += __shfl_xor(t, m, 64);
  if ((h & 63) == 0) red[h >> 6] = t;
  __syncthreads();
  if (h == 0) {
    float cc = 0.f;
#pragma unroll
    for (int i = 0; i < 8; ++i) cc += red[i];
    c_[p * NK + k] = cc;
  }
}

// ---------------- m97-style 128x128 GEMM-BT ----------------
// C[m][n] = sum_k A[m][k]*B[n][k].
// NPROD=3: A=Ah+Al,B=Bh+Bl split-fp16 (products k-major). NPROD=1: Ah*Bh only.
// EPI 0: relu(acc+bias) -> Oh/Ol f16 (ldo).  EPI 1: row partials of sum(z^2) -> part2.

template <int EPI, int NBN, int NPROD>
__global__ __launch_bounds__(256) void gemmA(
    const f16* __restrict__ Ah_, const f16* __restrict__ Al_, int lda, int apitch,
    const f16* __restrict__ Bh_, const f16* __restrict__ Bl_, int bpitch,
    const float* __restrict__ bias_, int bias_pitch,
    f16* __restrict__ Oh, f16* __restrict__ Ol, int ldo,
    float* __restrict__ part2) {
  __shared__ f16 smem[32768];  // 64 KB: 2 buf x [A 8192 | B 8192]
  const int tid = threadIdx.x;
  const int lane = tid & 63;
  const int wave = tid >> 6;
  const int wr = wave >> 1, wc = wave & 1;
  const int p = blockIdx.z;

  const int q8 = gridDim.x >> 3;
  const int bid = blockIdx.x;
  const int swz = (bid & 7) * q8 + (bid >> 3);
  const int bm = swz / NBN, bn = swz % NBN;
  const int m0 = bm * 128, n0 = bn * 128;

  const f16* Ahp = Ah_ + (size_t)p * apitch;
  const f16* Alp = Al_ + (size_t)p * apitch;
  const f16* Bhp = Bh_ + (size_t)p * bpitch;
  const f16* Blp = Bl_ + (size_t)p * bpitch;

  const int NT = (NPROD == 3) ? 24 : 8;

  f32x4 acc[4][4] = {};

  auto stage = [&](int buf, int t) {
    const f16* As;
    const f16* Bs;
    int k0;
    if (NPROD == 3) {
      int pr = t % 3;  // 0:(Ah,Bh) 1:(Ah,Bl) 2:(Al,Bh)
      As = (pr == 2) ? Alp : Ahp;
      Bs = (pr == 1) ? Blp : Bhp;
      k0 = (t / 3) * 64;
    } else {
      As = Ahp;
      Bs = Bhp;
      k0 = t * 64;
    }
    f16* sA = smem + buf * 16384;
    f16* sB = sA + 8192;
#pragma unroll
    for (int j = 0; j < 4; ++j) {
      int r = j * 32 + (tid >> 3);
      int c = ((tid & 7) ^ (r & 7)) * 8;  // pre-swizzled source col
      gload_lds16(As + (size_t)(m0 + r) * lda + k0 + c, sA + j * 2048 + tid * 8);
      gload_lds16(Bs + (size_t)(n0 + r) * 512 + k0 + c, sB + j * 2048 + tid * 8);
    }
  };

  stage(0, 0);
  __syncthreads();

  const int g = lane >> 4, rl = lane & 15;

  for (int s = 0; s < NT; ++s) {
    int nx = s + 1;
    if (nx < NT) stage(nx & 1, nx);
    const char* sA = (const char*)(smem + (s & 1) * 16384);
    const char* sB = sA + 16384;  // bytes
    f16x8 af[4][2], bf[4][2];
#pragma unroll
    for (int i = 0; i < 4; ++i) {
      int ra = wr * 64 + i * 16 + rl;
      int rb = wc * 64 + i * 16 + rl;
#pragma unroll
      for (int kk = 0; kk < 2; ++kk) {
        int cb = kk * 64 + g * 16;
        af[i][kk] = *(const f16x8*)(sA + ra * 128 + (cb ^ ((ra & 7) << 4)));
        bf[i][kk] = *(const f16x8*)(sB + rb * 128 + (cb ^ ((rb & 7) << 4)));
      }
    }
#pragma unroll
    for (int i = 0; i < 4; ++i)
#pragma unroll
      for (int jn = 0; jn < 4; ++jn)
#pragma unroll
        for (int kk = 0; kk < 2; ++kk)
          acc[i][jn] = __builtin_amdgcn_mfma_f32_16x16x32_f16(af[i][kk], bf[jn][kk], acc[i][jn], 0, 0, 0);
    __syncthreads();
  }

  if (EPI == 0) {
#pragma unroll
    for (int jn = 0; jn < 4; ++jn) {
      int cg = n0 + wc * 64 + jn * 16 + rl;
      float bv = bias_[cg];
#pragma unroll
      for (int i = 0; i < 4; ++i) {
        int r0 = m0 + wr * 64 + i * 16 + g * 4;
#pragma unroll
        for (int r = 0; r < 4; ++r) {
          float z = acc[i][jn][r] + bv;
          z = fmaxf(z, 0.f);
          f16 h = (f16)z;
          size_t off = (size_t)(r0 + r) * ldo + cg;
          Oh[off] = h;
          Ol[off] = (f16)(z - (float)h);
        }
      }
    }
  } else {
    const float* bp = bias_ + (size_t)p * bias_pitch;
    float bvals[4];
#pragma unroll
    for (int jn = 0; jn < 4; ++jn) bvals[jn] = bp[n0 + wc * 64 + jn * 16 + rl];
    const int ch = bn * 2 + wc;  // 0..7 (NBN=4)
    float* pb = part2 + (size_t)(p * 8 + ch) * B_ROWS;
#pragma unroll
    for (int i = 0; i < 4; ++i) {
#pragma unroll
      for (int r = 0; r < 4; ++r) {
        float q = 0.f;
#pragma unroll
        for (int jn = 0; jn < 4; ++jn) {
          float z = acc[i][jn][r] + bvals[jn];
          q = fmaf(z, z, q);
        }
#pragma unroll
        for (int m = 1; m < 16; m <<= 1) q += __shfl_xor(q, m, 64);
        if (rl == 0) pb[m0 + wr * 64 + i * 16 + g * 4 + r] = q;
      }
    }
  }
}

// ---------------- dots: g[p][b][k] = h[b]·Et[p][k] + c[p][k] ----------------

__global__ __launch_bounds__(256) void dots_kernel(const f16* __restrict__ Hh,
                                                   const f16* __restrict__ Hl,
                                                   const float* __restrict__ Et,
                                                   const float* __restrict__ c_,
                                                   float* __restrict__ g) {
  const int p = blockIdx.y;
  const int lane = threadIdx.x & 63, wave = threadIdx.x >> 6;
  float4 et[NK][2];
#pragma unroll
  for (int k = 0; k < NK; ++k) {
    const float* ep = Et + ((size_t)p * NK + k) * DIM + lane * 8;
    et[k][0] = *(const float4*)ep;
    et[k][1] = *(const float4*)(ep + 4);
  }
  float cv[NK];
#pragma unroll
  for (int k = 0; k < NK; ++k) cv[k] = c_[p * NK + k];
  const int r0 = blockIdx.x * 128 + wave * 32;
  for (int rr = 0; rr < 32; ++rr) {
    int row = r0 + rr;
    const f16* hhp = Hh + (size_t)row * 4096 + p * DIM + lane * 8;
    const f16* hlp = Hl + (size_t)row * 4096 + p * DIM + lane * 8;
    f16x8 hh = *(const f16x8*)hhp;
    f16x8 hl = *(const f16x8*)hlp;
    float h[8];
#pragma unroll
    for (int j = 0; j < 8; ++j) h[j] = (float)hh[j] + (float)hl[j];
    float d[NK];
#pragma unroll
    for (int k = 0; k < NK; ++k) {
      float s = h[0] * et[k][0].x;
      s = fmaf(h[1], et[k][0].y, s);
      s = fmaf(h[2], et[k][0].z, s);
      s = fmaf(h[3], et[k][0].w, s);
      s = fmaf(h[4], et[k][1].x, s);
      s = fmaf(h[5], et[k][1].y, s);
      s = fmaf(h[6], et[k][1].z, s);
      s = fmaf(h[7], et[k][1].w, s);
      d[k] = s;
    }
#pragma unroll
    for (int m = 1; m < 64; m <<= 1)
#pragma unroll
      for (int k = 0; k < NK; ++k) d[k] += __shfl_xor(d[k], m, 64);
    float* gp = g + ((size_t)p * B_ROWS + row) * NK;
#pragma unroll
    for (int k = 0; k < NK; ++k)
      if (lane == k) gp[k] = d[k] + cv[k];
  }
}

// ---------------- final: assemble dist + argmin + vq_z + loss + changed ----------------

__global__ __launch_bounds__(256) void final_kernel(
    const float* __restrict__ X, const float* __restrict__ part2,
    const float* __restrict__ g, const float* __restrict__ E2,
    const float* __restrict__ Emean, const float* __restrict__ E2m,
    const int* __restrict__ label, float* __restrict__ vq_z,
    float* __restrict__ dist, float* __restrict__ loss, float* __restrict__ changed) {
  __shared__ float Em[NK * DIM];
  __shared__ float e2s[NK];
  for (int i = threadIdx.x; i < NK * DIM; i += 256) Em[i] = Emean[i];
  if (threadIdx.x < NK) e2s[threadIdx.x] = E2m[threadIdx.x];
  __syncthreads();
  const int lane = threadIdx.x & 63, wave = threadIdx.x >> 6;
  const int pl = lane & 7, kh = lane >> 3;
  for (int rr = 0; rr < 4; ++rr) {
    int b = blockIdx.x * 16 + wave * 4 + rr;
    // zsq[p]: lane (pl, ch=kh) loads part2, xor-reduce over ch bits -> all lanes hold zsq[pl]
    float zq = part2[(size_t)(pl * 8 + kh) * B_ROWS + b];
    zq += __shfl_xor(zq, 8, 64);
    zq += __shfl_xor(zq, 16, 64);
    zq += __shfl_xor(zq, 32, 64);
    // distances: d[p][k] = zsq[p] + E2[p][k] - 2*g[p][b][k]
    float g0 = g[((size_t)pl * B_ROWS + b) * NK + kh];
    float g1 = (lane < 16) ? g[((size_t)pl * B_ROWS + b) * NK + 8 + kh] : 0.f;
    float dv0 = zq + E2[pl * NK + kh] - 2.f * g0;
    float dv1 = zq + E2[pl * NK + 8 + kh] - 2.f * g1;
    dist[((size_t)pl * B_ROWS + b) * NK + kh] = dv0;
    if (lane < 16) dist[((size_t)pl * B_ROWS + b) * NK + 8 + kh] = dv1;
    // sum over p (xor over low 3 bits)
    float v0 = dv0, v1 = dv1;
#pragma unroll
    for (int m = 1; m < 8; m <<= 1) {
      v0 += __shfl_xor(v0, m, 64);
      v1 += __shfl_xor(v1, m, 64);
    }
    float a[NK];
#pragma unroll
    for (int k = 0; k < 8; ++k) a[k] = __shfl(v0, k * 8, 64);
    a[8] = __shfl(v1, 0, 64);
    a[9] = __shfl(v1, 8, 64);
    int idx = 0;
    float mn = a[0];
#pragma unroll
    for (int k = 1; k < NK; ++k) {
      if (a[k] < mn) { mn = a[k]; idx = k; }
    }
    // x-dependent loss terms
    const float* xr = X + (size_t)b * DIM;
    float sx = 0.f, dx[NK] = {};
#pragma unroll
    for (int j = 0; j < 8; ++j) {
      float x = xr[j * 64 + lane];
      sx = fmaf(x, x, sx);
#pragma unroll
      for (int k = 0; k < NK; ++k) dx[k] = fmaf(x, Em[k * DIM + j * 64 + lane], dx[k]);
    }
#pragma unroll
    for (int m = 1; m < 64; m <<= 1) {
      sx += __shfl_xor(sx, m, 64);
#pragma unroll
      for (int k = 0; k < NK; ++k) dx[k] += __shfl_xor(dx[k], m, 64);
    }
    if (lane == 0) {
#pragma unroll
      for (int k = 0; k < NK; ++k)
        loss[(size_t)k * B_ROWS + b] = 1.25f * (sx - 2.f * dx[k] + e2s[k]);
    }
    int lab = label[b];
#pragma unroll
    for (int j = 0; j < 8; ++j) {
      int c = j * 64 + lane;
      vq_z[(size_t)b * DIM + c] = Em[idx * DIM + c];
      changed[(size_t)b * DIM + c] = Em[lab * DIM + c];
    }
  }
}

// ---------------- all_vq_z broadcast ----------------

__global__ void bcast_kernel(const float* __restrict__ Emean, float4* __restrict__ out) {
  const float4* Em4 = (const float4*)Emean;
  size_t n = (size_t)NK * B_ROWS * (DIM / 4);
  for (size_t i = (size_t)blockIdx.x * blockDim.x + threadIdx.x; i < n;
       i += (size_t)gridDim.x * blockDim.x) {
    size_t kb = i >> 7;
    int d4 = (int)(i & 127);
    int k = (int)(kb >> 15);
    out[i] = Em4[k * 128 + d4];
  }
}

// ---------------- launch ----------------

extern "C" void kernel_launch(void* const* d_in, const int* in_sizes, int n_in,
                              void* d_out, int out_size, void* d_ws, size_t ws_size,
                              hipStream_t stream) {
  const float* X = (const float*)d_in[0];
  const float* W1 = (const float*)d_in[1];
  const float* b1 = (const float*)d_in[2];
  const float* W2 = (const float*)d_in[3];
  const float* b2 = (const float*)d_in[4];
  const float* E = (const float*)d_in[5];
  const int* lab = (const int*)d_in[6];
  float* out = (float*)d_out;

  // output layout (flat f32, return order)
  float* vq_z = out;                               // 16,777,216
  float* dist = out + 16777216;                    // 2,621,440
  float* avz = out + 16777216 + 2621440;           // 167,772,160
  float* loss = avz + 167772160;                   // 327,680
  float* chg = loss + 327680;                      // 16,777,216

  // scratch carved from output regions (consumed before the final/bcast writes):
  f16* Xh = (f16*)vq_z;                       // 33.5 MB
  f16* Xl = Xh + 16777216;                    // fills vq_z region
  f16* Hh = (f16*)avz;                        // stacked H [32768][4096] f16 = 268 MB
  f16* Hl = Hh + 134217728;                   // +268 MB
  float* part2 = avz + 134217728;             // [8][8][32768] f32 = 8 MB (after H planes)
  float* gbuf = part2 + 2097152;              // [8][32768][10] f32 = 10.5 MB

  // small ws allocations (~17 MB)
  char* w = (char*)d_ws;
  f16* W1h = (f16*)w; w += 4194304;
  f16* W1l = (f16*)w; w += 4194304;
  f16* W2h = (f16*)w; w += 4194304;
  f16* W2l = (f16*)w; w += 4194304;
  float* Emean = (float*)w; w += NK * DIM * 4;
  float* E2 = (float*)w; w += 512;
  float* E2m = (float*)w; w += 256;
  float* Et = (float*)w; w += NP * NK * DIM * 4;  // 164 KB
  float* c_ = (float*)w; w += 512;

  split_kernel<<<2048, 256, 0, stream>>>(X, Xh, Xl, 16777216);
  split_kernel<<<512, 256, 0, stream>>>(W1, W1h, W1l, 2097152);
  split_kernel<<<512, 256, 0, stream>>>(W2, W2h, W2l, 2097152);
  emean_kernel<<<20, 256, 0, stream>>>(E, Emean);
  enorm_kernel<<<90, 64, 0, stream>>>(E, Emean, E2, E2m);
  etilde_kernel<<<80, 512, 0, stream>>>(W2, b2, E, Et, c_);

  // GEMM1: [32768x512] x [4096x512]^T -> stacked H (relu + f16 split), 3 products
  gemmA<0, 32, 3><<<dim3(8192, 1, 1), 256, 0, stream>>>(
      Xh, Xl, 512, 0, W1h, W1l, 0, b1, 0, Hh, Hl, 4096, nullptr);
  // GEMM2: per-p [32768x512] x [512x512]^T, 1 product (Hh*W2h) -> zsq partials
  gemmA<1, 4, 1><<<dim3(1024, 1, NP), 256, 0, stream>>>(
      Hh, Hh, 4096, 512, W2h, W2h, 262144, b2, 512, nullptr, nullptr, 0, part2);

  dots_kernel<<<dim3(256, NP), 256, 0, stream>>>(Hh, Hl, Et, c_, gbuf);
  final_kernel<<<2048, 256, 0, stream>>>(X, part2, gbuf, E2, Emean, E2m, lab,
                                         vq_z, dist, loss, chg);
  bcast_kernel<<<4096, 256, 0, stream>>>(Emean, (float4*)avz);
}

// Round 4
// 1140.035 us; speedup vs baseline: 1.4272x; 1.0957x over previous
//
#include <hip/hip_runtime.h>
#include <stdint.h>

typedef _Float16 f16;
typedef _Float16 f16x8 __attribute__((ext_vector_type(8)));
typedef float f32x4 __attribute__((ext_vector_type(4)));

#define B_ROWS 32768
#define DIM 512
#define NP 8
#define NK 10

typedef __attribute__((address_space(3))) unsigned int lds_u32;
typedef __attribute__((address_space(1))) const unsigned int gbl_u32;

__device__ __forceinline__ void gload_lds16(const void* g, void* l) {
  __builtin_amdgcn_global_load_lds((gbl_u32*)(uintptr_t)g, (lds_u32*)(uintptr_t)l, 16, 0, 0);
}

// ---------------- prep kernels ----------------

__global__ void split_kernel(const float* __restrict__ src, f16* __restrict__ hi,
                             f16* __restrict__ lo, int n) {
  int i = blockIdx.x * 256 + threadIdx.x;
  int stride = gridDim.x * 256;
  for (; i < n; i += stride) {
    float v = src[i];
    f16 h = (f16)v;
    hi[i] = h;
    lo[i] = (f16)(v - (float)h);
  }
}

__global__ void emean_kernel(const float* __restrict__ E, float* __restrict__ Emean) {
  int i = blockIdx.x * 256 + threadIdx.x;
  if (i < NK * DIM) {
    float s = 0.f;
#pragma unroll
    for (int p = 0; p < NP; ++p) s += E[p * NK * DIM + i];
    Emean[i] = s * 0.125f;
  }
}

__global__ void enorm_kernel(const float* __restrict__ E, const float* __restrict__ Emean,
                             float* __restrict__ E2, float* __restrict__ E2m) {
  int bid = blockIdx.x;  // 0..79 -> E2[p*10+k]; 80..89 -> E2m[k]
  const float* src = (bid < 80) ? (E + (size_t)bid * DIM) : (Emean + (size_t)(bid - 80) * DIM);
  int lane = threadIdx.x;  // block = 64
  float s = 0.f;
  for (int i = lane; i < DIM; i += 64) {
    float v = src[i];
    s = fmaf(v, v, s);
  }
#pragma unroll
  for (int m = 1; m < 64; m <<= 1) s += __shfl_xor(s, m, 64);
  if (lane == 0) {
    if (bid < 80) E2[bid] = s;
    else E2m[bid - 80] = s;
  }
}

// Et[p][k][h] = sum_d W2[p][d][h]*E[p][k][d];  c[p][k] = b2[p]·E[p][k]
__global__ __launch_bounds__(512) void etilde_kernel(const float* __restrict__ W2,
                                                     const float* __restrict__ b2,
                                                     const float* __restrict__ E,
                                                     float* __restrict__ Et,
                                                     float* __restrict__ c_) {
  const int p = blockIdx.x / NK, k = blockIdx.x % NK;
  const int h = threadIdx.x;  // 512 threads
  __shared__ float Er[512];
  __shared__ float red[8];
  Er[h] = E[((size_t)p * NK + k) * DIM + h];
  __syncthreads();
  const float* Wp = W2 + (size_t)p * DIM * DIM;
  float s = 0.f;
#pragma unroll 8
  for (int d = 0; d < DIM; ++d) s = fmaf(Wp[(size_t)d * DIM + h], Er[d], s);
  Et[((size_t)p * NK + k) * DIM + h] = s;
  float t = b2[p * DIM + h] * Er[h];
#pragma unroll
  for (int m = 1; m < 64; m <<= 1) t += __shfl_xor(t, m, 64);
  if ((h & 63) == 0) red[h >> 6] = t;
  __syncthreads();
  if (h == 0) {
    float cc = 0.f;
#pragma unroll
    for (int i = 0; i < 8; ++i) cc += red[i];
    c_[p * NK + k] = cc;
  }
}

// pack Et into padded fp16-split LDS images: [p][16][520], zeros in pads
__global__ void epack_kernel(const float* __restrict__ Et, f16* __restrict__ EimgH,
                             f16* __restrict__ EimgL) {
  int i = blockIdx.x * 256 + threadIdx.x;
  const int tot = NP * 16 * 520;
  if (i >= tot) return;
  int p = i / (16 * 520);
  int rem = i % (16 * 520);
  int k = rem / 520, h = rem % 520;
  float v = (k < NK && h < DIM) ? Et[((size_t)p * NK + k) * DIM + h] : 0.f;
  f16 hi = (f16)v;
  EimgH[i] = hi;
  EimgL[i] = (f16)(v - (float)hi);
}

// ---------------- m97-style 128x128 GEMM-BT ----------------
// C[m][n] = sum_k A[m][k]*B[n][k].
// NPROD=3: split-fp16 (Ah·Bh, Ah·Bl, Al·Bh k-major). NPROD=1: Ah·Bh only.
// GRP: L2 banding — XCD chunk walks 8-bm bands bm-fastest (A band L2-resident).
// EPI 0: relu(acc+bias) -> Oh/Ol f16.  EPI 1: row partials of sum(z^2) -> part2.

template <int EPI, int NBN, int NPROD, int GRP>
__global__ __launch_bounds__(256) void gemmA(
    const f16* __restrict__ Ah_, const f16* __restrict__ Al_, int lda, int apitch,
    const f16* __restrict__ Bh_, const f16* __restrict__ Bl_, int bpitch,
    const float* __restrict__ bias_, int bias_pitch,
    f16* __restrict__ Oh, f16* __restrict__ Ol, int ldo,
    float* __restrict__ part2) {
  __shared__ f16 smem[32768];  // 64 KB: 2 buf x [A 8192 | B 8192]
  const int tid = threadIdx.x;
  const int lane = tid & 63;
  const int wave = tid >> 6;
  const int wr = wave >> 1, wc = wave & 1;
  const int p = blockIdx.z;

  const int q8 = gridDim.x >> 3;
  const int bid = blockIdx.x;
  const int swz = (bid & 7) * q8 + (bid >> 3);
  const int band = swz / (GRP * NBN);
  const int r_ = swz % (GRP * NBN);
  const int bm = band * GRP + (r_ % GRP);
  const int bn = r_ / GRP;
  const int m0 = bm * 128, n0 = bn * 128;

  const f16* Ahp = Ah_ + (size_t)p * apitch;
  const f16* Alp = Al_ + (size_t)p * apitch;
  const f16* Bhp = Bh_ + (size_t)p * bpitch;
  const f16* Blp = Bl_ + (size_t)p * bpitch;

  const int NT = (NPROD == 3) ? 24 : 8;

  f32x4 acc[4][4] = {};

  auto stage = [&](int buf, int t) {
    const f16* As;
    const f16* Bs;
    int k0;
    if (NPROD == 3) {
      int pr = t % 3;  // 0:(Ah,Bh) 1:(Ah,Bl) 2:(Al,Bh)
      As = (pr == 2) ? Alp : Ahp;
      Bs = (pr == 1) ? Blp : Bhp;
      k0 = (t / 3) * 64;
    } else {
      As = Ahp;
      Bs = Bhp;
      k0 = t * 64;
    }
    f16* sA = smem + buf * 16384;
    f16* sB = sA + 8192;
#pragma unroll
    for (int j = 0; j < 4; ++j) {
      int r = j * 32 + (tid >> 3);
      int c = ((tid & 7) ^ (r & 7)) * 8;  // pre-swizzled source col
      gload_lds16(As + (size_t)(m0 + r) * lda + k0 + c, sA + j * 2048 + tid * 8);
      gload_lds16(Bs + (size_t)(n0 + r) * 512 + k0 + c, sB + j * 2048 + tid * 8);
    }
  };

  stage(0, 0);
  __syncthreads();

  const int g = lane >> 4, rl = lane & 15;

  for (int s = 0; s < NT; ++s) {
    int nx = s + 1;
    if (nx < NT) stage(nx & 1, nx);
    const char* sA = (const char*)(smem + (s & 1) * 16384);
    const char* sB = sA + 16384;  // bytes
    f16x8 af[4][2], bf[4][2];
#pragma unroll
    for (int i = 0; i < 4; ++i) {
      int ra = wr * 64 + i * 16 + rl;
      int rb = wc * 64 + i * 16 + rl;
#pragma unroll
      for (int kk = 0; kk < 2; ++kk) {
        int cb = kk * 64 + g * 16;
        af[i][kk] = *(const f16x8*)(sA + ra * 128 + (cb ^ ((ra & 7) << 4)));
        bf[i][kk] = *(const f16x8*)(sB + rb * 128 + (cb ^ ((rb & 7) << 4)));
      }
    }
#pragma unroll
    for (int i = 0; i < 4; ++i)
#pragma unroll
      for (int jn = 0; jn < 4; ++jn)
#pragma unroll
        for (int kk = 0; kk < 2; ++kk)
          acc[i][jn] = __builtin_amdgcn_mfma_f32_16x16x32_f16(af[i][kk], bf[jn][kk], acc[i][jn], 0, 0, 0);
    __syncthreads();
  }

  if (EPI == 0) {
#pragma unroll
    for (int jn = 0; jn < 4; ++jn) {
      int cg = n0 + wc * 64 + jn * 16 + rl;
      float bv = bias_[cg];
#pragma unroll
      for (int i = 0; i < 4; ++i) {
        int r0 = m0 + wr * 64 + i * 16 + g * 4;
#pragma unroll
        for (int r = 0; r < 4; ++r) {
          float z = acc[i][jn][r] + bv;
          z = fmaxf(z, 0.f);
          f16 h = (f16)z;
          size_t off = (size_t)(r0 + r) * ldo + cg;
          Oh[off] = h;
          Ol[off] = (f16)(z - (float)h);
        }
      }
    }
  } else {
    const float* bp = bias_ + (size_t)p * bias_pitch;
    float bvals[4];
#pragma unroll
    for (int jn = 0; jn < 4; ++jn) bvals[jn] = bp[n0 + wc * 64 + jn * 16 + rl];
    const int ch = bn * 2 + wc;  // 0..7 (NBN=4)
    float* pb = part2 + (size_t)(p * 8 + ch) * B_ROWS;
#pragma unroll
    for (int i = 0; i < 4; ++i) {
#pragma unroll
      for (int r = 0; r < 4; ++r) {
        float q = 0.f;
#pragma unroll
        for (int jn = 0; jn < 4; ++jn) {
          float z = acc[i][jn][r] + bvals[jn];
          q = fmaf(z, z, q);
        }
#pragma unroll
        for (int m = 1; m < 16; m <<= 1) q += __shfl_xor(q, m, 64);
        if (rl == 0) pb[m0 + wr * 64 + i * 16 + g * 4 + r] = q;
      }
    }
  }
}

// ---------------- dots via skinny MFMA: g[p][b][k] = h[b]·Et[p][k] + c[p][k] ----------------
// A = H (split planes), B = Et[p] padded to [16][520] fp16-split. 3 products.

__global__ __launch_bounds__(256) void dots_mfma(const f16* __restrict__ Hh,
                                                 const f16* __restrict__ Hl,
                                                 const f16* __restrict__ EimgH,
                                                 const f16* __restrict__ EimgL,
                                                 const float* __restrict__ c_,
                                                 float* __restrict__ gout) {
  __shared__ f16 sH[8192];        // 128x64 swizzled tile
  __shared__ f16 sL[8192];
  __shared__ f16 sEh[16 * 520];   // padded rows: 1040 B stride
  __shared__ f16 sEl[16 * 520];
  const int tid = threadIdx.x;
  const int lane = tid & 63, wave = tid >> 6;
  const int p = blockIdx.y;
  const int r0 = blockIdx.x * 128;
  {
    const uint32_t* ih = (const uint32_t*)(EimgH + (size_t)p * 16 * 520);
    const uint32_t* il = (const uint32_t*)(EimgL + (size_t)p * 16 * 520);
    uint32_t* oh = (uint32_t*)sEh;
    uint32_t* ol = (uint32_t*)sEl;
    for (int i = tid; i < 16 * 520 / 2; i += 256) {
      oh[i] = ih[i];
      ol[i] = il[i];
    }
  }
  const int gq = lane >> 4, rl = lane & 15;
  f32x4 acc[2] = {};
  for (int t = 0; t < 8; ++t) {
    __syncthreads();  // prev tile's reads done (and E copy visible at t=0)
#pragma unroll
    for (int j = 0; j < 4; ++j) {
      int r = j * 32 + (tid >> 3);
      int c = ((tid & 7) ^ (r & 7)) * 8;
      gload_lds16(Hh + (size_t)(r0 + r) * 4096 + p * DIM + t * 64 + c, sH + j * 2048 + tid * 8);
      gload_lds16(Hl + (size_t)(r0 + r) * 4096 + p * DIM + t * 64 + c, sL + j * 2048 + tid * 8);
    }
    __syncthreads();  // drains vmcnt (compiler) -> tiles resident
    const char* bh = (const char*)sH;
    const char* bl = (const char*)sL;
    const char* eh = (const char*)sEh;
    const char* el = (const char*)sEl;
    f16x8 ah[2][2], al[2][2], beh[2], bel[2];
#pragma unroll
    for (int mf = 0; mf < 2; ++mf) {
      int ra = wave * 32 + mf * 16 + rl;
#pragma unroll
      for (int kk = 0; kk < 2; ++kk) {
        int cb = kk * 64 + gq * 16;
        ah[mf][kk] = *(const f16x8*)(bh + ra * 128 + (cb ^ ((ra & 7) << 4)));
        al[mf][kk] = *(const f16x8*)(bl + ra * 128 + (cb ^ ((ra & 7) << 4)));
      }
    }
#pragma unroll
    for (int kk = 0; kk < 2; ++kk) {
      int cb = t * 128 + kk * 64 + gq * 16;
      beh[kk] = *(const f16x8*)(eh + rl * 1040 + cb);
      bel[kk] = *(const f16x8*)(el + rl * 1040 + cb);
    }
#pragma unroll
    for (int mf = 0; mf < 2; ++mf)
#pragma unroll
      for (int kk = 0; kk < 2; ++kk) {
        acc[mf] = __builtin_amdgcn_mfma_f32_16x16x32_f16(ah[mf][kk], beh[kk], acc[mf], 0, 0, 0);
        acc[mf] = __builtin_amdgcn_mfma_f32_16x16x32_f16(ah[mf][kk], bel[kk], acc[mf], 0, 0, 0);
        acc[mf] = __builtin_amdgcn_mfma_f32_16x16x32_f16(al[mf][kk], beh[kk], acc[mf], 0, 0, 0);
      }
  }
  if (rl < NK) {
    float cv = c_[p * NK + rl];
#pragma unroll
    for (int mf = 0; mf < 2; ++mf)
#pragma unroll
      for (int r = 0; r < 4; ++r) {
        int row = r0 + wave * 32 + mf * 16 + gq * 4 + r;
        gout[((size_t)p * B_ROWS + row) * NK + rl] = acc[mf][r] + cv;
      }
  }
}

// ---------------- final: assemble dist + argmin + vq_z + loss + changed ----------------

__global__ __launch_bounds__(256) void final_kernel(
    const float* __restrict__ X, const float* __restrict__ part2,
    const float* __restrict__ g, const float* __restrict__ E2,
    const float* __restrict__ Emean, const float* __restrict__ E2m,
    const int* __restrict__ label, float* __restrict__ vq_z,
    float* __restrict__ dist, float* __restrict__ loss, float* __restrict__ changed) {
  __shared__ float Em[NK * DIM];
  __shared__ float e2s[NK];
  for (int i = threadIdx.x; i < NK * DIM; i += 256) Em[i] = Emean[i];
  if (threadIdx.x < NK) e2s[threadIdx.x] = E2m[threadIdx.x];
  __syncthreads();
  const int lane = threadIdx.x & 63, wave = threadIdx.x >> 6;
  const int pl = lane & 7, kh = lane >> 3;
  for (int rr = 0; rr < 4; ++rr) {
    int b = blockIdx.x * 16 + wave * 4 + rr;
    float zq = part2[(size_t)(pl * 8 + kh) * B_ROWS + b];
    zq += __shfl_xor(zq, 8, 64);
    zq += __shfl_xor(zq, 16, 64);
    zq += __shfl_xor(zq, 32, 64);
    float g0 = g[((size_t)pl * B_ROWS + b) * NK + kh];
    float g1 = (lane < 16) ? g[((size_t)pl * B_ROWS + b) * NK + 8 + kh] : 0.f;
    float dv0 = zq + E2[pl * NK + kh] - 2.f * g0;
    float dv1 = zq + E2[pl * NK + 8 + kh] - 2.f * g1;
    dist[((size_t)pl * B_ROWS + b) * NK + kh] = dv0;
    if (lane < 16) dist[((size_t)pl * B_ROWS + b) * NK + 8 + kh] = dv1;
    float v0 = dv0, v1 = dv1;
#pragma unroll
    for (int m = 1; m < 8; m <<= 1) {
      v0 += __shfl_xor(v0, m, 64);
      v1 += __shfl_xor(v1, m, 64);
    }
    float a[NK];
#pragma unroll
    for (int k = 0; k < 8; ++k) a[k] = __shfl(v0, k * 8, 64);
    a[8] = __shfl(v1, 0, 64);
    a[9] = __shfl(v1, 8, 64);
    int idx = 0;
    float mn = a[0];
#pragma unroll
    for (int k = 1; k < NK; ++k) {
      if (a[k] < mn) { mn = a[k]; idx = k; }
    }
    const float* xr = X + (size_t)b * DIM;
    float sx = 0.f, dx[NK] = {};
#pragma unroll
    for (int j = 0; j < 8; ++j) {
      float x = xr[j * 64 + lane];
      sx = fmaf(x, x, sx);
#pragma unroll
      for (int k = 0; k < NK; ++k) dx[k] = fmaf(x, Em[k * DIM + j * 64 + lane], dx[k]);
    }
#pragma unroll
    for (int m = 1; m < 64; m <<= 1) {
      sx += __shfl_xor(sx, m, 64);
#pragma unroll
      for (int k = 0; k < NK; ++k) dx[k] += __shfl_xor(dx[k], m, 64);
    }
    if (lane == 0) {
#pragma unroll
      for (int k = 0; k < NK; ++k)
        loss[(size_t)k * B_ROWS + b] = 1.25f * (sx - 2.f * dx[k] + e2s[k]);
    }
    int lab = label[b];
#pragma unroll
    for (int j = 0; j < 8; ++j) {
      int c = j * 64 + lane;
      vq_z[(size_t)b * DIM + c] = Em[idx * DIM + c];
      changed[(size_t)b * DIM + c] = Em[lab * DIM + c];
    }
  }
}

// ---------------- all_vq_z broadcast ----------------

__global__ void bcast_kernel(const float* __restrict__ Emean, float4* __restrict__ out) {
  const float4* Em4 = (const float4*)Emean;
  size_t n = (size_t)NK * B_ROWS * (DIM / 4);
  for (size_t i = (size_t)blockIdx.x * blockDim.x + threadIdx.x; i < n;
       i += (size_t)gridDim.x * blockDim.x) {
    size_t kb = i >> 7;
    int d4 = (int)(i & 127);
    int k = (int)(kb >> 15);
    out[i] = Em4[k * 128 + d4];
  }
}

// ---------------- launch ----------------

extern "C" void kernel_launch(void* const* d_in, const int* in_sizes, int n_in,
                              void* d_out, int out_size, void* d_ws, size_t ws_size,
                              hipStream_t stream) {
  const float* X = (const float*)d_in[0];
  const float* W1 = (const float*)d_in[1];
  const float* b1 = (const float*)d_in[2];
  const float* W2 = (const float*)d_in[3];
  const float* b2 = (const float*)d_in[4];
  const float* E = (const float*)d_in[5];
  const int* lab = (const int*)d_in[6];
  float* out = (float*)d_out;

  // output layout (flat f32, return order)
  float* vq_z = out;                               // 16,777,216
  float* dist = out + 16777216;                    // 2,621,440
  float* avz = out + 16777216 + 2621440;           // 167,772,160
  float* loss = avz + 167772160;                   // 327,680
  float* chg = loss + 327680;                      // 16,777,216

  // scratch carved from output regions (consumed before the final/bcast writes):
  f16* Xh = (f16*)vq_z;                       // 33.5 MB
  f16* Xl = Xh + 16777216;                    // fills vq_z region
  f16* Hh = (f16*)avz;                        // stacked H [32768][4096] f16 = 268 MB
  f16* Hl = Hh + 134217728;                   // +268 MB
  float* part2 = avz + 134217728;             // [8][8][32768] f32 = 8 MB
  float* gbuf = part2 + 2097152;              // [8][32768][10] f32 = 10.5 MB

  // small ws allocations (~17.5 MB)
  char* w = (char*)d_ws;
  f16* W1h = (f16*)w; w += 4194304;
  f16* W1l = (f16*)w; w += 4194304;
  f16* W2h = (f16*)w; w += 4194304;
  f16* W2l = (f16*)w; w += 4194304;
  float* Emean = (float*)w; w += NK * DIM * 4;
  float* E2 = (float*)w; w += 512;
  float* E2m = (float*)w; w += 256;
  float* Et = (float*)w; w += NP * NK * DIM * 4;  // 164 KB
  float* c_ = (float*)w; w += 512;
  f16* EimgH = (f16*)w; w += NP * 16 * 520 * 2;   // 133 KB
  f16* EimgL = (f16*)w; w += NP * 16 * 520 * 2;

  split_kernel<<<2048, 256, 0, stream>>>(X, Xh, Xl, 16777216);
  split_kernel<<<512, 256, 0, stream>>>(W1, W1h, W1l, 2097152);
  split_kernel<<<512, 256, 0, stream>>>(W2, W2h, W2l, 2097152);
  emean_kernel<<<20, 256, 0, stream>>>(E, Emean);
  enorm_kernel<<<90, 64, 0, stream>>>(E, Emean, E2, E2m);
  etilde_kernel<<<80, 512, 0, stream>>>(W2, b2, E, Et, c_);
  epack_kernel<<<260, 256, 0, stream>>>(Et, EimgH, EimgL);

  // GEMM1: [32768x512] x [4096x512]^T -> stacked H (relu + f16 split), 3 products
  gemmA<0, 32, 3, 8><<<dim3(8192, 1, 1), 256, 0, stream>>>(
      Xh, Xl, 512, 0, W1h, W1l, 0, b1, 0, Hh, Hl, 4096, nullptr);
  // GEMM2: per-p [32768x512] x [512x512]^T, 1 product (Hh*W2h) -> zsq partials
  gemmA<1, 4, 1, 1><<<dim3(1024, 1, NP), 256, 0, stream>>>(
      Hh, Hh, 4096, 512, W2h, W2h, 262144, b2, 512, nullptr, nullptr, 0, part2);

  dots_mfma<<<dim3(256, NP), 256, 0, stream>>>(Hh, Hl, EimgH, EimgL, c_, gbuf);
  final_kernel<<<2048, 256, 0, stream>>>(X, part2, gbuf, E2, Emean, E2m, lab,
                                         vq_z, dist, loss, chg);
  bcast_kernel<<<4096, 256, 0, stream>>>(Emean, (float4*)avz);
}